// Round 7
// baseline (131.035 us; speedup 1.0000x reference)
//
#include <hip/hip_runtime.h>
#include <hip/hip_bf16.h>
#include <math.h>

// Problem constants: B=2, T=2048, C=1024, H=16, D=64
#define T_SEQ 2048
#define NHEAD 16
#define HDIM  64
#define CDIM  1024
#define KDIM  1024
// softmax runs in exp2 domain; SCALE*log2(e) folded into Q at GEMM epilogue
#define SCALE_L2E 0.1803368801111204f

typedef __attribute__((ext_vector_type(8))) short bf16x8;
typedef __attribute__((ext_vector_type(4))) float f32x4;
typedef __attribute__((ext_vector_type(16))) float f32x16;
typedef __attribute__((ext_vector_type(8))) unsigned short u16x8;
typedef __attribute__((ext_vector_type(4))) unsigned int u32x4;

__device__ __forceinline__ unsigned short f2bf(float f) {
    unsigned int u = __builtin_bit_cast(unsigned int, f);
    u += 0x7fffu + ((u >> 16) & 1u);   // round-to-nearest-even
    return (unsigned short)(u >> 16);
}
__device__ __forceinline__ unsigned int cvt_pk_bf16(float lo, float hi_) {
    unsigned int r;
    asm("v_cvt_pk_bf16_f32 %0, %1, %2" : "=v"(r) : "v"(lo), "v"(hi_));
    return r;
}
__device__ __forceinline__ void pl32swap(unsigned int &a, unsigned int &b) {
    asm("v_permlane32_swap_b32 %0, %1" : "+v"(a), "+v"(b));
}
// async global->LDS, 16B per lane; LDS dest is wave-uniform base + lane*16
__device__ __forceinline__ void gld16(const unsigned short* g, unsigned short* l) {
    __builtin_amdgcn_global_load_lds(
        (const __attribute__((address_space(1))) unsigned int*)g,
        (__attribute__((address_space(3))) unsigned int*)l,
        16, 0, 0);
}

// ---------------------------------------------------------------------------
// prep: x f32 -> bf16 (same layout)
// ---------------------------------------------------------------------------
__global__ __launch_bounds__(256) void prep_x(const float* __restrict__ x,
                                              unsigned short* __restrict__ Xb) {
    size_t i = ((size_t)blockIdx.x * 256 + threadIdx.x) * 8;
    float4 a = *(const float4*)(x + i);
    float4 b = *(const float4*)(x + i + 4);
    u32x4 o;
    o[0] = cvt_pk_bf16(a.x, a.y);
    o[1] = cvt_pk_bf16(a.z, a.w);
    o[2] = cvt_pk_bf16(b.x, b.y);
    o[3] = cvt_pk_bf16(b.z, b.w);
    *(u32x4*)(Xb + i) = o;
}

// ---------------------------------------------------------------------------
// prep: W f32 [K=1024][NC] -> Wt bf16 [NC][1024]  (64x64 LDS tile transpose)
// ---------------------------------------------------------------------------
template<int NC>
__global__ __launch_bounds__(256) void prep_w(const float* __restrict__ W,
                                              unsigned short* __restrict__ Wt) {
    __shared__ unsigned short Ls[64][72];
    const int n0 = blockIdx.x * 64, k0 = blockIdx.y * 64;
    const int t = threadIdx.x;
    {
        int kr = t >> 2, nc = (t & 3) * 16;
        #pragma unroll
        for (int j = 0; j < 4; j++) {
            float4 v = *(const float4*)(W + (size_t)(k0 + kr) * NC + n0 + nc + j * 4);
            Ls[nc + j*4 + 0][kr] = f2bf(v.x);
            Ls[nc + j*4 + 1][kr] = f2bf(v.y);
            Ls[nc + j*4 + 2][kr] = f2bf(v.z);
            Ls[nc + j*4 + 3][kr] = f2bf(v.w);
        }
    }
    __syncthreads();
    {
        int nr = t >> 2, kc = (t & 3) * 16;
        u16x8 o0 = *(const u16x8*)&Ls[nr][kc];
        u16x8 o1 = *(const u16x8*)&Ls[nr][kc + 8];
        *(u16x8*)(Wt + (size_t)(n0 + nr) * KDIM + k0 + kc)     = o0;
        *(u16x8*)(Wt + (size_t)(n0 + nr) * KDIM + k0 + kc + 8) = o1;
    }
}

// ---------------------------------------------------------------------------
// GEMM: C[4096, NC] = A[4096,1024]bf16 @ Wt[NC,1024]bf16^T + bias
// m97 structure: 128x128 tile, 4 waves, BK=64, global_load_lds w16 staging
// with pre-swizzled source + XOR-swizzled ds_read (both-sides involution).
// (verbatim from R5-passing build)
// ---------------------------------------------------------------------------
template<int NC, int EPI>
__global__ __launch_bounds__(256) void gemm_k(
    const unsigned short* __restrict__ A, const unsigned short* __restrict__ Wt,
    const float* __restrict__ bias, float* __restrict__ Of,
    unsigned short* __restrict__ Qb, unsigned short* __restrict__ Kb,
    unsigned short* __restrict__ Vt)
{
    __shared__ unsigned short As[128 * 64];   // swizzled content, linear layout
    __shared__ unsigned short Bs[128 * 64];

    const int tid  = threadIdx.x;
    const int lane = tid & 63;
    const int wid  = tid >> 6;
    const int m0 = blockIdx.x * 128;
    const int n0 = blockIdx.y * 128;
    const int wm = (wid >> 1) * 64;
    const int wn = (wid & 1) * 64;
    const int rl = lane & 15;

    // staging geometry: wave stages rows wid*32 + 8c + (lane>>3); slot = lane&7
    const int r8 = lane >> 3, s8 = lane & 7;
    const int swzs = (s8 ^ r8) * 8;           // pre-swizzled source elem offset

    f32x4 acc[4][4] = {};

    for (int k0 = 0; k0 < KDIM; k0 += 64) {
        #pragma unroll
        for (int c = 0; c < 4; c++) {
            int row = (wid << 5) + (c << 3) + r8;
            gld16(A  + (size_t)(m0 + row) * KDIM + k0 + swzs, &As[(size_t)((wid<<5)+(c<<3)) * 64]);
            gld16(Wt + (size_t)(n0 + row) * KDIM + k0 + swzs, &Bs[(size_t)((wid<<5)+(c<<3)) * 64]);
        }
        __syncthreads();   // drains vmcnt: tile ready
        #pragma unroll
        for (int kc = 0; kc < 2; kc++) {
            const int sb = kc * 4 + (lane >> 4);      // base slot of this k-chunk
            bf16x8 af[4], bfr[4];
            #pragma unroll
            for (int f = 0; f < 4; f++) {
                int sw = (sb ^ (rl & 7)) * 8;
                af[f]  = *(const bf16x8*)&As[(wm + f*16 + rl) * 64 + sw];
                bfr[f] = *(const bf16x8*)&Bs[(wn + f*16 + rl) * 64 + sw];
            }
            __builtin_amdgcn_s_setprio(1);
            #pragma unroll
            for (int i = 0; i < 4; i++)
                #pragma unroll
                for (int j = 0; j < 4; j++)
                    acc[i][j] = __builtin_amdgcn_mfma_f32_16x16x32_bf16(af[i], bfr[j], acc[i][j], 0, 0, 0);
            __builtin_amdgcn_s_setprio(0);
        }
        __syncthreads();
    }

    #pragma unroll
    for (int j = 0; j < 4; j++) {
        int gn = n0 + wn + j*16 + rl;
        float bv = bias[gn];
        #pragma unroll
        for (int i = 0; i < 4; i++) {
            int gm0 = m0 + wm + i*16 + (lane >> 4) * 4;
            #pragma unroll
            for (int r = 0; r < 4; r++) {
                float v = acc[i][j][r] + bv;
                int gm = gm0 + r;
                if (EPI == 0) {
                    int which = gn >> 10;          // 0=q 1=k 2=v
                    int cw = gn & 1023;
                    int h = cw >> 6, d = cw & 63;
                    int b = gm >> 11, t = gm & 2047;
                    size_t bh = (size_t)(b * NHEAD + h);
                    if (which == 0)      Qb[(bh * T_SEQ + t) * HDIM + d] = f2bf(v * SCALE_L2E);
                    else if (which == 1) Kb[(bh * T_SEQ + t) * HDIM + d] = f2bf(v);
                    else                 Vt[(bh * HDIM + d) * T_SEQ + t] = f2bf(v);
                } else {
                    Of[(size_t)gm * NC + gn] = v;
                }
            }
        }
    }
}

// ---------------------------------------------------------------------------
// Causal flash attention. 2 waves = 64 q-rows per block; 32 q-tiles
// heavy-first -> 1024 blocks (~5 resident/CU). KVBLK=64, double-buffered
// global_load_lds with a DRAIN pipeline: per tile, vmcnt(0)+barrier (tile
// ready, zero outstanding), issue next-tile stage, compute, barrier.
// No vmcnt counting; zero in-flight loads at kernel exit.
// XOR-swizzled K/V LDS. Swapped-QK^T 32x32, lane-local exp2 softmax,
// defer-max, cvt_pk+permlane P packing.
// ---------------------------------------------------------------------------
__global__ __launch_bounds__(128) void attn_k(
    const unsigned short* __restrict__ Qb, const unsigned short* __restrict__ Kb,
    const unsigned short* __restrict__ Vt, unsigned short* __restrict__ AO)
{
    // tile buffer: K[64 rows][64 el swz] 8KB + V[64 d-rows][64 el swz] 8KB
    __shared__ unsigned short sbuf[2 * 8192];

    const int tid  = threadIdx.x;
    const int lane = tid & 63;
    const int w    = tid >> 6;                  // 0..1
    const int bh   = blockIdx.x;                // 0..31
    const int qt   = 31 - blockIdx.y;           // heavy q-tiles dispatched first
    const int q0w  = qt * 64 + w * 32;
    const int ql   = lane & 31;
    const int hi   = lane >> 5;
    const int qg   = q0w + ql;
    const int nt   = qt + 1;                    // 64-kv tiles

    const unsigned short* Qp = Qb + (size_t)bh * T_SEQ * HDIM;
    const unsigned short* Kp = Kb + (size_t)bh * T_SEQ * HDIM;
    const unsigned short* Vp = Vt + (size_t)bh * HDIM * T_SEQ;

    // staging role: wave 0 stages K (64 rows), wave 1 stages V (64 d-rows)
    const int r8 = lane >> 3, s8 = lane & 7;
    const int swzs = (s8 ^ r8) * 8;
    const unsigned short* sp0;
    size_t stepE, cstep;
    int dstbase;
    if (w == 0) {
        sp0 = Kp + (size_t)r8 * HDIM + swzs;
        stepE = 64 * HDIM; cstep = 8 * HDIM;
        dstbase = 0;
    } else {
        sp0 = Vp + (size_t)r8 * T_SEQ + swzs;
        stepE = 64; cstep = 8 * T_SEQ;
        dstbase = 4096;
    }

    // Q fragments (held all kernel)
    bf16x8 qf[4];
    #pragma unroll
    for (int dc = 0; dc < 4; dc++)
        qf[dc] = *(const bf16x8*)(Qp + (size_t)qg * HDIM + dc*16 + hi*8);

    float m_run = -INFINITY, l_run = 0.f;
    f32x16 o0 = {}, o1 = {};

    // prologue: stage tile 0 -> buf 0
    #pragma unroll
    for (int c = 0; c < 8; c++)
        gld16(sp0 + c * cstep, &sbuf[dstbase + c * 512]);

    for (int t = 0; t < nt; ++t) {
        const int c0 = t << 6;
        asm volatile("s_waitcnt vmcnt(0)" ::: "memory");   // tile t fully landed
        __builtin_amdgcn_s_barrier();                      // visible to both waves
        __builtin_amdgcn_sched_barrier(0);

        // issue next-tile stage now; lands under this tile's compute.
        // Safe: buf[(t+1)&1]'s readers finished at iteration t-1's end barrier.
        if (t + 1 < nt) {
            #pragma unroll
            for (int c = 0; c < 8; c++)
                gld16(sp0 + (size_t)(t + 1) * stepE + c * cstep,
                      &sbuf[((t + 1) & 1) * 8192 + dstbase + c * 512]);
        }

        const char* kb = (const char*)sbuf + (t & 1) * 16384;
        const char* vb = kb + 8192;
        const bool a1 = (c0 + 32 <= q0w);

        // ---- S^T = K·(Q*scale)^T for chunk0 (+chunk1 if active) ----
        f32x16 s0 = {}, s1 = {};
        __builtin_amdgcn_s_setprio(1);
        #pragma unroll
        for (int dc = 0; dc < 4; dc++) {
            int sw = (((dc << 1) | hi) ^ (ql & 7)) << 4;
            bf16x8 kf = *(const bf16x8*)(kb + ql*128 + sw);
            s0 = __builtin_amdgcn_mfma_f32_32x32x16_bf16(kf, qf[dc], s0, 0, 0, 0);
        }
        if (a1) {
            #pragma unroll
            for (int dc = 0; dc < 4; dc++) {
                int sw = (((dc << 1) | hi) ^ (ql & 7)) << 4;
                bf16x8 kf = *(const bf16x8*)(kb + 4096 + ql*128 + sw);
                s1 = __builtin_amdgcn_mfma_f32_32x32x16_bf16(kf, qf[dc], s1, 0, 0, 0);
            }
        }
        __builtin_amdgcn_s_setprio(0);

        // ---- masks (diagonal chunks only; wave-uniform branches) ----
        float pm0[16], pm1[16];
        #pragma unroll
        for (int r = 0; r < 16; r++) { pm0[r] = s0[r]; pm1[r] = s1[r]; }
        if (c0 == q0w) {
            #pragma unroll
            for (int r = 0; r < 16; r++) {
                int kv = c0 + (r & 3) + 8 * (r >> 2) + 4 * hi;
                pm0[r] = (kv > qg) ? -INFINITY : pm0[r];
            }
        }
        if (a1 && (c0 + 32 == q0w)) {
            #pragma unroll
            for (int r = 0; r < 16; r++) {
                int kv = c0 + 32 + (r & 3) + 8 * (r >> 2) + 4 * hi;
                pm1[r] = (kv > qg) ? -INFINITY : pm1[r];
            }
        }

        // ---- combined online softmax over the 64-kv tile ----
        float tm = pm0[0];
        #pragma unroll
        for (int r = 1; r < 16; r++) tm = fmaxf(tm, pm0[r]);
        if (a1) {
            #pragma unroll
            for (int r = 0; r < 16; r++) tm = fmaxf(tm, pm1[r]);
        }
        tm = fmaxf(tm, __shfl_xor(tm, 32));
        if (__any(tm > m_run + 11.5f)) {       // defer-max (T13)
            float mn = fmaxf(m_run, tm);
            float sf = exp2f(m_run - mn);
            m_run = mn;
            l_run *= sf;
            #pragma unroll
            for (int r = 0; r < 16; r++) { o0[r] *= sf; o1[r] *= sf; }
        }
        float p0[16], p1[16]; float rs = 0.f;
        #pragma unroll
        for (int r = 0; r < 16; r++) { p0[r] = exp2f(pm0[r] - m_run); rs += p0[r]; }
        if (a1) {
            #pragma unroll
            for (int r = 0; r < 16; r++) { p1[r] = exp2f(pm1[r] - m_run); rs += p1[r]; }
        }
        rs += __shfl_xor(rs, 32);
        l_run += rs;

        // ---- V frags (swizzled LDS) ----
        const int swv0 = ((0 + hi) ^ (ql & 7)) << 4;
        const int swv1 = ((2 + hi) ^ (ql & 7)) << 4;
        const int swv2 = ((4 + hi) ^ (ql & 7)) << 4;
        const int swv3 = ((6 + hi) ^ (ql & 7)) << 4;
        const char* vrow0 = vb + ql * 128;
        const char* vrow1 = vb + (32 + ql) * 128;

        // ---- pack P chunk0: 8 cvt_pk + 4 permlane32_swap ----
        unsigned int c[8];
        #pragma unroll
        for (int i = 0; i < 8; i++) c[i] = cvt_pk_bf16(p0[2*i], p0[2*i+1]);
        pl32swap(c[0], c[2]);  pl32swap(c[1], c[3]);
        pl32swap(c[4], c[6]);  pl32swap(c[5], c[7]);
        u32x4 b0 = {c[0], c[1], c[2], c[3]};
        u32x4 b1 = {c[4], c[5], c[6], c[7]};
        bf16x8 pf0 = __builtin_bit_cast(bf16x8, b0);
        bf16x8 pf1 = __builtin_bit_cast(bf16x8, b1);

        bf16x8 v00 = *(const bf16x8*)(vrow0 + swv0);
        bf16x8 v01 = *(const bf16x8*)(vrow0 + swv1);
        bf16x8 v10 = *(const bf16x8*)(vrow1 + swv0);
        bf16x8 v11 = *(const bf16x8*)(vrow1 + swv1);
        __builtin_amdgcn_s_setprio(1);
        o0 = __builtin_amdgcn_mfma_f32_32x32x16_bf16(v00, pf0, o0, 0, 0, 0);
        o0 = __builtin_amdgcn_mfma_f32_32x32x16_bf16(v01, pf1, o0, 0, 0, 0);
        o1 = __builtin_amdgcn_mfma_f32_32x32x16_bf16(v10, pf0, o1, 0, 0, 0);
        o1 = __builtin_amdgcn_mfma_f32_32x32x16_bf16(v11, pf1, o1, 0, 0, 0);
        __builtin_amdgcn_s_setprio(0);

        if (a1) {
            #pragma unroll
            for (int i = 0; i < 8; i++) c[i] = cvt_pk_bf16(p1[2*i], p1[2*i+1]);
            pl32swap(c[0], c[2]);  pl32swap(c[1], c[3]);
            pl32swap(c[4], c[6]);  pl32swap(c[5], c[7]);
            u32x4 b2 = {c[0], c[1], c[2], c[3]};
            u32x4 b3 = {c[4], c[5], c[6], c[7]};
            bf16x8 pf2 = __builtin_bit_cast(bf16x8, b2);
            bf16x8 pf3 = __builtin_bit_cast(bf16x8, b3);
            bf16x8 v02 = *(const bf16x8*)(vrow0 + swv2);
            bf16x8 v03 = *(const bf16x8*)(vrow0 + swv3);
            bf16x8 v12 = *(const bf16x8*)(vrow1 + swv2);
            bf16x8 v13 = *(const bf16x8*)(vrow1 + swv3);
            __builtin_amdgcn_s_setprio(1);
            o0 = __builtin_amdgcn_mfma_f32_32x32x16_bf16(v02, pf2, o0, 0, 0, 0);
            o0 = __builtin_amdgcn_mfma_f32_32x32x16_bf16(v03, pf3, o0, 0, 0, 0);
            o1 = __builtin_amdgcn_mfma_f32_32x32x16_bf16(v12, pf2, o1, 0, 0, 0);
            o1 = __builtin_amdgcn_mfma_f32_32x32x16_bf16(v13, pf3, o1, 0, 0, 0);
            __builtin_amdgcn_s_setprio(0);
        }

        __builtin_amdgcn_sched_barrier(0);
        __builtin_amdgcn_s_barrier();      // readers of buf[t&1] done
    }

    // ---- epilogue: O^T[d][q] -> AO[b, t=qg, h*64+d], packed 8B stores ----
    const float inv_l = 1.f / l_run;
    const int b = bh >> 4, h = bh & 15;
    unsigned short* aop = AO + ((size_t)(b * T_SEQ + qg)) * CDIM + h * HDIM;
    #pragma unroll
    for (int qd = 0; qd < 4; qd++) {
        uint2 w0, w1;
        w0.x = cvt_pk_bf16(o0[4*qd+0] * inv_l, o0[4*qd+1] * inv_l);
        w0.y = cvt_pk_bf16(o0[4*qd+2] * inv_l, o0[4*qd+3] * inv_l);
        w1.x = cvt_pk_bf16(o1[4*qd+0] * inv_l, o1[4*qd+1] * inv_l);
        w1.y = cvt_pk_bf16(o1[4*qd+2] * inv_l, o1[4*qd+3] * inv_l);
        *(uint2*)(aop + qd*8 + hi*4)      = w0;
        *(uint2*)(aop + 32 + qd*8 + hi*4) = w1;
    }
}

// ---------------------------------------------------------------------------
extern "C" void kernel_launch(void* const* d_in, const int* in_sizes, int n_in,
                              void* d_out, int out_size, void* d_ws, size_t ws_size,
                              hipStream_t stream) {
    const float* x      = (const float*)d_in[0];
    const float* w_qkv  = (const float*)d_in[1];
    const float* b_qkv  = (const float*)d_in[2];
    const float* w_proj = (const float*)d_in[3];
    const float* b_proj = (const float*)d_in[4];
    float* out = (float*)d_out;

    const size_t MI = (size_t)1 << 20;
    unsigned short* base = (unsigned short*)d_ws;
    unsigned short* Qb  = base;
    unsigned short* Kb  = base + 4*MI;
    unsigned short* Vt  = base + 8*MI;
    unsigned short* Wqt = base + 12*MI;
    unsigned short* Wpt = base + 15*MI;
    unsigned short* Xb  = base + 16*MI;
    unsigned short* AO  = Xb;   // Xb dead after QKV gemm

    prep_x<<<dim3(2048), 256, 0, stream>>>(x, Xb);
    prep_w<3072><<<dim3(48, 16), 256, 0, stream>>>(w_qkv, Wqt);
    prep_w<1024><<<dim3(16, 16), 256, 0, stream>>>(w_proj, Wpt);
    gemm_k<3072, 0><<<dim3(32, 24), 256, 0, stream>>>(
        Xb, Wqt, b_qkv, nullptr, Qb, Kb, Vt);
    attn_k<<<dim3(32, 32), 128, 0, stream>>>(Qb, Kb, Vt, AO);
    gemm_k<1024, 1><<<dim3(32, 8), 256, 0, stream>>>(
        AO, Wpt, b_proj, out, nullptr, nullptr, nullptr);
}

// Round 9
// 118.779 us; speedup vs baseline: 1.1032x; 1.1032x over previous
//
#include <hip/hip_runtime.h>
#include <hip/hip_bf16.h>
#include <math.h>

// Problem constants: B=2, T=2048, C=1024, H=16, D=64
#define T_SEQ 2048
#define NHEAD 16
#define HDIM  64
#define CDIM  1024
#define KDIM  1024
// softmax runs in exp2 domain; SCALE*log2(e) folded into Q at GEMM epilogue
#define SCALE_L2E 0.1803368801111204f

typedef __attribute__((ext_vector_type(8))) short bf16x8;
typedef __attribute__((ext_vector_type(4))) float f32x4;
typedef __attribute__((ext_vector_type(16))) float f32x16;
typedef __attribute__((ext_vector_type(8))) unsigned short u16x8;
typedef __attribute__((ext_vector_type(4))) unsigned int u32x4;

__device__ __forceinline__ unsigned short f2bf(float f) {
    unsigned int u = __builtin_bit_cast(unsigned int, f);
    u += 0x7fffu + ((u >> 16) & 1u);   // round-to-nearest-even
    return (unsigned short)(u >> 16);
}
__device__ __forceinline__ unsigned int cvt_pk_bf16(float lo, float hi_) {
    unsigned int r;
    asm("v_cvt_pk_bf16_f32 %0, %1, %2" : "=v"(r) : "v"(lo), "v"(hi_));
    return r;
}
__device__ __forceinline__ void pl32swap(unsigned int &a, unsigned int &b) {
    asm("v_permlane32_swap_b32 %0, %1" : "+v"(a), "+v"(b));
}
// async global->LDS, 16B per lane; LDS dest is wave-uniform base + lane*16
__device__ __forceinline__ void gld16(const unsigned short* g, unsigned short* l) {
    __builtin_amdgcn_global_load_lds(
        (const __attribute__((address_space(1))) unsigned int*)g,
        (__attribute__((address_space(3))) unsigned int*)l,
        16, 0, 0);
}

// ---------------------------------------------------------------------------
// prep: x f32 -> bf16 (same layout)
// ---------------------------------------------------------------------------
__global__ __launch_bounds__(256) void prep_x(const float* __restrict__ x,
                                              unsigned short* __restrict__ Xb) {
    size_t i = ((size_t)blockIdx.x * 256 + threadIdx.x) * 8;
    float4 a = *(const float4*)(x + i);
    float4 b = *(const float4*)(x + i + 4);
    u32x4 o;
    o[0] = cvt_pk_bf16(a.x, a.y);
    o[1] = cvt_pk_bf16(a.z, a.w);
    o[2] = cvt_pk_bf16(b.x, b.y);
    o[3] = cvt_pk_bf16(b.z, b.w);
    *(u32x4*)(Xb + i) = o;
}

// ---------------------------------------------------------------------------
// prep: W f32 [K=1024][NC] -> Wt bf16 [NC][1024]  (64x64 LDS tile transpose)
// ---------------------------------------------------------------------------
template<int NC>
__global__ __launch_bounds__(256) void prep_w(const float* __restrict__ W,
                                              unsigned short* __restrict__ Wt) {
    __shared__ unsigned short Ls[64][72];
    const int n0 = blockIdx.x * 64, k0 = blockIdx.y * 64;
    const int t = threadIdx.x;
    {
        int kr = t >> 2, nc = (t & 3) * 16;
        #pragma unroll
        for (int j = 0; j < 4; j++) {
            float4 v = *(const float4*)(W + (size_t)(k0 + kr) * NC + n0 + nc + j * 4);
            Ls[nc + j*4 + 0][kr] = f2bf(v.x);
            Ls[nc + j*4 + 1][kr] = f2bf(v.y);
            Ls[nc + j*4 + 2][kr] = f2bf(v.z);
            Ls[nc + j*4 + 3][kr] = f2bf(v.w);
        }
    }
    __syncthreads();
    {
        int nr = t >> 2, kc = (t & 3) * 16;
        u16x8 o0 = *(const u16x8*)&Ls[nr][kc];
        u16x8 o1 = *(const u16x8*)&Ls[nr][kc + 8];
        *(u16x8*)(Wt + (size_t)(n0 + nr) * KDIM + k0 + kc)     = o0;
        *(u16x8*)(Wt + (size_t)(n0 + nr) * KDIM + k0 + kc + 8) = o1;
    }
}

// ---------------------------------------------------------------------------
// GEMM: C[4096, NC] = A[4096,1024]bf16 @ Wt[NC,1024]bf16^T + bias
// m97 structure: 128x128 tile, 4 waves, BK=64, global_load_lds w16 staging
// with pre-swizzled source + XOR-swizzled ds_read (both-sides involution).
// (verbatim from R7-passing build)
// ---------------------------------------------------------------------------
template<int NC, int EPI>
__global__ __launch_bounds__(256) void gemm_k(
    const unsigned short* __restrict__ A, const unsigned short* __restrict__ Wt,
    const float* __restrict__ bias, float* __restrict__ Of,
    unsigned short* __restrict__ Qb, unsigned short* __restrict__ Kb,
    unsigned short* __restrict__ Vt)
{
    __shared__ unsigned short As[128 * 64];   // swizzled content, linear layout
    __shared__ unsigned short Bs[128 * 64];

    const int tid  = threadIdx.x;
    const int lane = tid & 63;
    const int wid  = tid >> 6;
    const int m0 = blockIdx.x * 128;
    const int n0 = blockIdx.y * 128;
    const int wm = (wid >> 1) * 64;
    const int wn = (wid & 1) * 64;
    const int rl = lane & 15;

    const int r8 = lane >> 3, s8 = lane & 7;
    const int swzs = (s8 ^ r8) * 8;           // pre-swizzled source elem offset

    f32x4 acc[4][4] = {};

    for (int k0 = 0; k0 < KDIM; k0 += 64) {
        #pragma unroll
        for (int c = 0; c < 4; c++) {
            int row = (wid << 5) + (c << 3) + r8;
            gld16(A  + (size_t)(m0 + row) * KDIM + k0 + swzs, &As[(size_t)((wid<<5)+(c<<3)) * 64]);
            gld16(Wt + (size_t)(n0 + row) * KDIM + k0 + swzs, &Bs[(size_t)((wid<<5)+(c<<3)) * 64]);
        }
        __syncthreads();   // drains vmcnt: tile ready
        #pragma unroll
        for (int kc = 0; kc < 2; kc++) {
            const int sb = kc * 4 + (lane >> 4);      // base slot of this k-chunk
            bf16x8 af[4], bfr[4];
            #pragma unroll
            for (int f = 0; f < 4; f++) {
                int sw = (sb ^ (rl & 7)) * 8;
                af[f]  = *(const bf16x8*)&As[(wm + f*16 + rl) * 64 + sw];
                bfr[f] = *(const bf16x8*)&Bs[(wn + f*16 + rl) * 64 + sw];
            }
            __builtin_amdgcn_s_setprio(1);
            #pragma unroll
            for (int i = 0; i < 4; i++)
                #pragma unroll
                for (int j = 0; j < 4; j++)
                    acc[i][j] = __builtin_amdgcn_mfma_f32_16x16x32_bf16(af[i], bfr[j], acc[i][j], 0, 0, 0);
            __builtin_amdgcn_s_setprio(0);
        }
        __syncthreads();
    }

    #pragma unroll
    for (int j = 0; j < 4; j++) {
        int gn = n0 + wn + j*16 + rl;
        float bv = bias[gn];
        #pragma unroll
        for (int i = 0; i < 4; i++) {
            int gm0 = m0 + wm + i*16 + (lane >> 4) * 4;
            #pragma unroll
            for (int r = 0; r < 4; r++) {
                float v = acc[i][j][r] + bv;
                int gm = gm0 + r;
                if (EPI == 0) {
                    int which = gn >> 10;          // 0=q 1=k 2=v
                    int cw = gn & 1023;
                    int h = cw >> 6, d = cw & 63;
                    int b = gm >> 11, t = gm & 2047;
                    size_t bh = (size_t)(b * NHEAD + h);
                    if (which == 0)      Qb[(bh * T_SEQ + t) * HDIM + d] = f2bf(v * SCALE_L2E);
                    else if (which == 1) Kb[(bh * T_SEQ + t) * HDIM + d] = f2bf(v);
                    else                 Vt[(bh * HDIM + d) * T_SEQ + t] = f2bf(v);
                } else {
                    Of[(size_t)gm * NC + gn] = v;
                }
            }
        }
    }
}

// ---------------------------------------------------------------------------
// Causal flash attention, split-KV: block = 2 INDEPENDENT waves sharing the
// same 32 q-rows; wave w does kv tiles t===w (mod 2), KVBLK=32. No barriers
// in the loop. Per-wave 8KB LDS buffer; pipeline = wait vmcnt(0) -> ds_read
// whole tile to regs -> lgkmcnt(0) -> issue next tile gld16 (same buffer) ->
// compute from regs. Final merge of (m,l,O) via __syncthreads + LDS.
// RACE FIX vs R8: a barrier BEFORE wave-1's merge writes — the merge scratch
// overlays wave-0's staging buffer, which was still live mid-loop.
// 4096 waves total (4/SIMD). Swapped-QK^T 32x32, lane-local exp2 softmax,
// defer-max, cvt_pk+permlane P packing. Grid 32 x 64 heavy-first.
// ---------------------------------------------------------------------------
__global__ __launch_bounds__(128, 4) void attn_k(
    const unsigned short* __restrict__ Qb, const unsigned short* __restrict__ Kb,
    const unsigned short* __restrict__ Vt, unsigned short* __restrict__ AO)
{
    // per wave: K[32 rows][64 el swz] 4KB + V[64 d-rows][32 el swz] 4KB
    __shared__ unsigned short sbuf[2 * 4096];

    const int tid  = threadIdx.x;
    const int lane = tid & 63;
    const int w    = tid >> 6;                  // 0..1
    const int bh   = blockIdx.x;                // 0..31
    const int qt   = 63 - blockIdx.y;           // heavy q-tiles dispatched first
    const int ql   = lane & 31;
    const int hi   = lane >> 5;
    const int qg   = (qt << 5) + ql;

    const unsigned short* Qp = Qb + (size_t)bh * T_SEQ * HDIM;
    const unsigned short* Kp = Kb + (size_t)bh * T_SEQ * HDIM;
    const unsigned short* Vp = Vt + (size_t)bh * HDIM * T_SEQ;

    unsigned short* kbuf = sbuf + w * 4096;     // this wave's buffer (elems)
    const char* kbB = (const char*)kbuf;              // K bytes
    const char* vbB = (const char*)(kbuf + 2048);     // V bytes

    // staging sources (pre-swizzled): K 8 rows/gld16, V 16 d-rows/gld16
    const int r8 = lane >> 3, s8 = lane & 7;
    const int r4 = lane >> 2, s4 = lane & 3;
    const unsigned short* kSrc = Kp + (size_t)r8 * HDIM + ((s8 ^ r8) << 3);
    const unsigned short* vSrc = Vp + (size_t)r4 * T_SEQ + ((s4 ^ (r4 & 3)) << 3);

    auto issue_tile = [&](int t) {
        #pragma unroll
        for (int c = 0; c < 4; c++)             // K: t*32 rows -> t*2048 elems
            gld16(kSrc + ((size_t)t << 11) + (c << 9), kbuf + (c << 9));
        #pragma unroll
        for (int c = 0; c < 4; c++)             // V: c*16 d-rows, col t*32
            gld16(vSrc + ((size_t)c << 15) + (t << 5), kbuf + 2048 + (c << 9));
    };

    // Q fragments (held all kernel)
    bf16x8 qf[4];
    #pragma unroll
    for (int dc = 0; dc < 4; dc++)
        qf[dc] = *(const bf16x8*)(Qp + (size_t)qg * HDIM + dc*16 + hi*8);

    float m_run = -INFINITY, l_run = 0.f;
    f32x16 o0 = {}, o1 = {};

    if (w <= qt) {
        issue_tile(w);
        for (int t = w; t <= qt; t += 2) {
            asm volatile("s_waitcnt vmcnt(0)" ::: "memory");   // tile t landed
            __builtin_amdgcn_sched_barrier(0);

            // ---- whole tile -> registers (8 x ds_read_b128) ----
            bf16x8 kf[4];
            #pragma unroll
            for (int dc = 0; dc < 4; dc++)
                kf[dc] = *(const bf16x8*)(kbB + ql*128 + (((dc << 1 | hi) ^ (ql & 7)) << 4));
            bf16x8 v00 = *(const bf16x8*)(vbB + ql*64        + (((0 | hi) ^ (ql & 3)) << 4));
            bf16x8 v01 = *(const bf16x8*)(vbB + ql*64        + (((2 | hi) ^ (ql & 3)) << 4));
            bf16x8 v10 = *(const bf16x8*)(vbB + (32+ql)*64   + (((0 | hi) ^ (ql & 3)) << 4));
            bf16x8 v11 = *(const bf16x8*)(vbB + (32+ql)*64   + (((2 | hi) ^ (ql & 3)) << 4));
            asm volatile("s_waitcnt lgkmcnt(0)" ::: "memory");
            __builtin_amdgcn_sched_barrier(0);

            if (t + 2 <= qt) issue_tile(t + 2);   // lands under compute

            // ---- S^T = K·(Q*scale)^T ----
            f32x16 s = {};
            __builtin_amdgcn_s_setprio(1);
            #pragma unroll
            for (int dc = 0; dc < 4; dc++)
                s = __builtin_amdgcn_mfma_f32_32x32x16_bf16(kf[dc], qf[dc], s, 0, 0, 0);
            __builtin_amdgcn_s_setprio(0);

            float p[16];
            #pragma unroll
            for (int r = 0; r < 16; r++) p[r] = s[r];
            if (t == qt) {                        // diagonal tile only
                #pragma unroll
                for (int r = 0; r < 16; r++) {
                    int kv = (t << 5) + (r & 3) + 8 * (r >> 2) + 4 * hi;
                    p[r] = (kv > qg) ? -INFINITY : p[r];
                }
            }
            float tm = p[0];
            #pragma unroll
            for (int r = 1; r < 16; r++) tm = fmaxf(tm, p[r]);
            tm = fmaxf(tm, __shfl_xor(tm, 32));
            if (__any(tm > m_run + 11.5f)) {      // defer-max (T13)
                float mn = fmaxf(m_run, tm);
                float sf = exp2f(m_run - mn);
                m_run = mn;
                l_run *= sf;
                #pragma unroll
                for (int r = 0; r < 16; r++) { o0[r] *= sf; o1[r] *= sf; }
            }
            float rs = 0.f;
            #pragma unroll
            for (int r = 0; r < 16; r++) { p[r] = exp2f(p[r] - m_run); rs += p[r]; }
            rs += __shfl_xor(rs, 32);
            l_run += rs;

            // ---- pack P: 8 cvt_pk + 4 permlane32_swap ----
            unsigned int c[8];
            #pragma unroll
            for (int i = 0; i < 8; i++) c[i] = cvt_pk_bf16(p[2*i], p[2*i+1]);
            pl32swap(c[0], c[2]);  pl32swap(c[1], c[3]);
            pl32swap(c[4], c[6]);  pl32swap(c[5], c[7]);
            u32x4 b0 = {c[0], c[1], c[2], c[3]};
            u32x4 b1 = {c[4], c[5], c[6], c[7]};
            bf16x8 pf0 = __builtin_bit_cast(bf16x8, b0);
            bf16x8 pf1 = __builtin_bit_cast(bf16x8, b1);

            // ---- O^T += V^T · P^T ----
            __builtin_amdgcn_s_setprio(1);
            o0 = __builtin_amdgcn_mfma_f32_32x32x16_bf16(v00, pf0, o0, 0, 0, 0);
            o0 = __builtin_amdgcn_mfma_f32_32x32x16_bf16(v01, pf1, o0, 0, 0, 0);
            o1 = __builtin_amdgcn_mfma_f32_32x32x16_bf16(v10, pf0, o1, 0, 0, 0);
            o1 = __builtin_amdgcn_mfma_f32_32x32x16_bf16(v11, pf1, o1, 0, 0, 0);
            __builtin_amdgcn_s_setprio(0);
        }
    }

    // ---- merge the two waves' partials (lane-aligned), wave0 writes out ----
    // Both waves have vmcnt=0 here (final tile drained at its loop top; no
    // further issues). Barrier BEFORE the writes: merge scratch overlays
    // wave-0's staging buffer (this was R8's race).
    __syncthreads();
    float* lf = (float*)sbuf;
    if (w == 1) {
        #pragma unroll
        for (int j = 0; j < 4; j++) {
            f32x4 a = { o0[4*j], o0[4*j+1], o0[4*j+2], o0[4*j+3] };
            *(f32x4*)(lf + (size_t)(j*64 + lane) * 4) = a;
        }
        #pragma unroll
        for (int j = 0; j < 4; j++) {
            f32x4 a = { o1[4*j], o1[4*j+1], o1[4*j+2], o1[4*j+3] };
            *(f32x4*)(lf + (size_t)((4+j)*64 + lane) * 4) = a;
        }
        lf[2048 + lane*2]     = m_run;
        lf[2048 + lane*2 + 1] = l_run;
    }
    __syncthreads();
    if (w == 0) {
        float m1 = lf[2048 + lane*2], l1 = lf[2048 + lane*2 + 1];
        float m  = fmaxf(m_run, m1);
        float sc0 = exp2f(m_run - m), sc1 = exp2f(m1 - m);
        float linv = 1.f / (l_run * sc0 + l1 * sc1);
        float a0 = sc0 * linv, a1 = sc1 * linv;
        const int b = bh >> 4, h = bh & 15;
        unsigned short* aop = AO + ((size_t)(b * T_SEQ + qg)) * CDIM + h * HDIM;
        #pragma unroll
        for (int qd = 0; qd < 4; qd++) {
            f32x4 x0 = *(const f32x4*)(lf + (size_t)(qd*64 + lane) * 4);
            f32x4 x1 = *(const f32x4*)(lf + (size_t)((4+qd)*64 + lane) * 4);
            uint2 w0, w1;
            w0.x = cvt_pk_bf16(o0[4*qd+0]*a0 + x0[0]*a1, o0[4*qd+1]*a0 + x0[1]*a1);
            w0.y = cvt_pk_bf16(o0[4*qd+2]*a0 + x0[2]*a1, o0[4*qd+3]*a0 + x0[3]*a1);
            w1.x = cvt_pk_bf16(o1[4*qd+0]*a0 + x1[0]*a1, o1[4*qd+1]*a0 + x1[1]*a1);
            w1.y = cvt_pk_bf16(o1[4*qd+2]*a0 + x1[2]*a1, o1[4*qd+3]*a0 + x1[3]*a1);
            *(uint2*)(aop + qd*8 + hi*4)      = w0;
            *(uint2*)(aop + 32 + qd*8 + hi*4) = w1;
        }
    }
}

// ---------------------------------------------------------------------------
extern "C" void kernel_launch(void* const* d_in, const int* in_sizes, int n_in,
                              void* d_out, int out_size, void* d_ws, size_t ws_size,
                              hipStream_t stream) {
    const float* x      = (const float*)d_in[0];
    const float* w_qkv  = (const float*)d_in[1];
    const float* b_qkv  = (const float*)d_in[2];
    const float* w_proj = (const float*)d_in[3];
    const float* b_proj = (const float*)d_in[4];
    float* out = (float*)d_out;

    const size_t MI = (size_t)1 << 20;
    unsigned short* base = (unsigned short*)d_ws;
    unsigned short* Qb  = base;
    unsigned short* Kb  = base + 4*MI;
    unsigned short* Vt  = base + 8*MI;
    unsigned short* Wqt = base + 12*MI;
    unsigned short* Wpt = base + 15*MI;
    unsigned short* Xb  = base + 16*MI;
    unsigned short* AO  = Xb;   // Xb dead after QKV gemm

    prep_x<<<dim3(2048), 256, 0, stream>>>(x, Xb);
    prep_w<3072><<<dim3(48, 16), 256, 0, stream>>>(w_qkv, Wqt);
    prep_w<1024><<<dim3(16, 16), 256, 0, stream>>>(w_proj, Wpt);
    gemm_k<3072, 0><<<dim3(32, 24), 256, 0, stream>>>(
        Xb, Wqt, b_qkv, nullptr, Qb, Kb, Vt);
    attn_k<<<dim3(32, 64), 128, 0, stream>>>(Qb, Kb, Vt, AO);
    gemm_k<1024, 1><<<dim3(32, 8), 256, 0, stream>>>(
        AO, Wpt, b_proj, out, nullptr, nullptr, nullptr);
}